// Round 12
// baseline (1193.180 us; speedup 1.0000x reference)
//
#include <hip/hip_runtime.h>
#include <hip/hip_bf16.h>

#define N_NODES 400000
#define N_EDGES 800000
#define DIM 128
#define NLAYER 5
#define BN_EPS 1e-5f

typedef _Float16 half8 __attribute__((ext_vector_type(8)));
typedef _Float16 half4 __attribute__((ext_vector_type(4)));
typedef float f32x4 __attribute__((ext_vector_type(4)));

// ---------------- embedding: h0 = emb_atom[x0] + emb_chir[x1] (fp16 out) ----------------
__global__ __launch_bounds__(256) void k_embed(const int* __restrict__ x,
                                               const float* __restrict__ ea,
                                               const float* __restrict__ ec,
                                               _Float16* __restrict__ out) {
  int idx = blockIdx.x * 256 + threadIdx.x;      // 8-col chunk
  int i = idx >> 4, c8 = (idx & 15) * 8;
  int av = x[2 * i], cv = x[2 * i + 1];
  float4 a0 = *(const float4*)(ea + (size_t)av * DIM + c8);
  float4 a1 = *(const float4*)(ea + (size_t)av * DIM + c8 + 4);
  float4 c0 = *(const float4*)(ec + (size_t)cv * DIM + c8);
  float4 c1 = *(const float4*)(ec + (size_t)cv * DIM + c8 + 4);
  half8 r;
  r[0] = (_Float16)(a0.x + c0.x); r[1] = (_Float16)(a0.y + c0.y);
  r[2] = (_Float16)(a0.z + c0.z); r[3] = (_Float16)(a0.w + c0.w);
  r[4] = (_Float16)(a1.x + c1.x); r[5] = (_Float16)(a1.y + c1.y);
  r[6] = (_Float16)(a1.z + c1.z); r[7] = (_Float16)(a1.w + c1.w);
  *(half8*)(out + (size_t)i * DIM + c8) = r;
}

// ---------------- CSR build ----------------
__global__ __launch_bounds__(256) void k_hist(const int* __restrict__ dst, int* __restrict__ cnt) {
  int e = blockIdx.x * 256 + threadIdx.x;
  if (e < N_EDGES) atomicAdd(&cnt[dst[e]], 1);
}

__global__ __launch_bounds__(256) void k_scan1(const int* __restrict__ cnt, int* __restrict__ rp,
                                               int* __restrict__ part) {
  __shared__ int sm[256];
  int t = threadIdx.x;
  int base = blockIdx.x * 1024 + t * 4;
  int v0 = 0, v1 = 0, v2 = 0, v3 = 0;
  if (base + 4 <= N_NODES) {
    int4 v = *(const int4*)(cnt + base);
    v0 = v.x; v1 = v.y; v2 = v.z; v3 = v.w;
  } else {
    if (base     < N_NODES) v0 = cnt[base];
    if (base + 1 < N_NODES) v1 = cnt[base + 1];
    if (base + 2 < N_NODES) v2 = cnt[base + 2];
    if (base + 3 < N_NODES) v3 = cnt[base + 3];
  }
  int s = v0 + v1 + v2 + v3;
  sm[t] = s;
  __syncthreads();
  for (int off = 1; off < 256; off <<= 1) {
    int add = (t >= off) ? sm[t - off] : 0;
    __syncthreads();
    sm[t] += add;
    __syncthreads();
  }
  int incl = sm[t];
  int ex = incl - s;
  if (t == 255) part[blockIdx.x] = incl;
  if (base     < N_NODES) rp[base]     = ex;
  if (base + 1 < N_NODES) rp[base + 1] = ex + v0;
  if (base + 2 < N_NODES) rp[base + 2] = ex + v0 + v1;
  if (base + 3 < N_NODES) rp[base + 3] = ex + v0 + v1 + v2;
}

__global__ __launch_bounds__(512) void k_scan2(int* __restrict__ part, int nb) {
  __shared__ int sm[512];
  int t = threadIdx.x;
  int v = (t < nb) ? part[t] : 0;
  sm[t] = v;
  __syncthreads();
  for (int off = 1; off < 512; off <<= 1) {
    int add = (t >= off) ? sm[t - off] : 0;
    __syncthreads();
    sm[t] += add;
    __syncthreads();
  }
  if (t < nb) part[t] = sm[t] - v;   // exclusive
}

__global__ __launch_bounds__(256) void k_scan3(int* __restrict__ rp, const int* __restrict__ part) {
  int i = blockIdx.x * 256 + threadIdx.x;
  if (i < N_NODES) rp[i] += part[i >> 10];
  if (i == 0) rp[N_NODES] = N_EDGES;
}

__global__ __launch_bounds__(256) void k_scatter(const int* __restrict__ src, const int* __restrict__ dst,
                                                 const int* __restrict__ rp, int* __restrict__ fill,
                                                 int* __restrict__ es) {
  int e = blockIdx.x * 256 + threadIdx.x;
  if (e < N_EDGES) {
    int d = dst[e];
    int slot = rp[d] + atomicAdd(&fill[d], 1);
    es[slot] = src[e];
  }
}

// ---------------- W pre-transpose to fp16: wt[l][mat][c][k] = W[l][k][c] ----------------
__global__ __launch_bounds__(128) void k_wprep(const float* __restrict__ W1, const float* __restrict__ W2,
                                               _Float16* __restrict__ wt) {
  int b = blockIdx.x;                 // 5*2*128
  int l = b >> 8, mat = (b >> 7) & 1, c = b & 127;
  int k = threadIdx.x;                // 128
  const float* W = mat ? W2 : W1;
  float v = W[(size_t)l * DIM * DIM + (size_t)k * DIM + c];
  wt[((size_t)(l * 2 + mat) * DIM + c) * DIM + k] = (_Float16)v;
}

// ---------------- fused layer: X = T(P)+sum T(P[nbr]);  Z = relu(X@W1+b1)@W2+b2 + BN stats
// Block = 64 rows. Each row aggregated by its 4 fragment-threads (16 rows/wave in parallel).
// 48KB LDS, W staged twice -> 3 blocks/CU.
template <int UA>
__global__ __launch_bounds__(256) void k_layer(const _Float16* __restrict__ P,
                                               const int* __restrict__ rp,
                                               const int* __restrict__ es,
                                               const float* __restrict__ affine,
                                               const _Float16* __restrict__ wt,
                                               const float* __restrict__ b1, const float* __restrict__ b2,
                                               _Float16* __restrict__ Z, float* __restrict__ stats) {
  __shared__ _Float16 sh[16384 + 64 * DIM];   // wbuf (32KB) | tbuf (16KB) = 48KB
  _Float16* wbuf = sh;
  _Float16* tb   = sh + 16384;

  const int tid = threadIdx.x;
  const int lane = tid & 63, w = tid >> 6;
  const int l15 = lane & 15, h = lane >> 4;
  const half8* wg = (const half8*)wt;

  // stage W1^T to LDS (XOR-swizzled rows)
#pragma unroll
  for (int i = 0; i < 8; ++i) {
    int h8 = i * 256 + tid;            // 0..2047
    half8 v = wg[h8];
    int cc = h8 >> 4, k8 = h8 & 15;
    int hidx = (cc * DIM + k8 * 8) ^ ((cc & 7) << 3);
    *(half8*)(wbuf + hidx) = v;
  }

  // affine coefficients for this thread's 32 cols (4 chunks of 8 at kt*32+8h)
  float af[4][8], cf[4][8];
  if (UA) {
#pragma unroll
    for (int kt = 0; kt < 4; ++kt) {
      int k0 = kt * 32 + 8 * h;
      float4 t0 = *(const float4*)(affine + k0);
      float4 t1 = *(const float4*)(affine + k0 + 4);
      float4 u0 = *(const float4*)(affine + DIM + k0);
      float4 u1 = *(const float4*)(affine + DIM + k0 + 4);
      af[kt][0] = t0.x; af[kt][1] = t0.y; af[kt][2] = t0.z; af[kt][3] = t0.w;
      af[kt][4] = t1.x; af[kt][5] = t1.y; af[kt][6] = t1.z; af[kt][7] = t1.w;
      cf[kt][0] = u0.x; cf[kt][1] = u0.y; cf[kt][2] = u0.z; cf[kt][3] = u0.w;
      cf[kt][4] = u1.x; cf[kt][5] = u1.y; cf[kt][6] = u1.z; cf[kt][7] = u1.w;
    }
  }

  // ---- aggregation: acc = T(P[row]) + sum_nbr T(P[nbr]) (fp32) ----
  const int row = blockIdx.x * 64 + 16 * w + l15;
  const size_t rbase = (size_t)row * DIM + 8 * h;
  const int e0 = rp[row], e1 = rp[row + 1];
  float acc[4][8];
#pragma unroll
  for (int kt = 0; kt < 4; ++kt) {
    half8 sv = *(const half8*)(P + rbase + kt * 32);
#pragma unroll
    for (int i = 0; i < 8; ++i) {
      float v = (float)sv[i];
      acc[kt][i] = UA ? fmaxf(fmaf(af[kt][i], v, cf[kt][i]), 0.f) : v;
    }
  }
  for (int e = e0; e < e1; ++e) {
    const size_t nb = (size_t)es[e] * DIM + 8 * h;
    half8 v0 = *(const half8*)(P + nb);
    half8 v1 = *(const half8*)(P + nb + 32);
    half8 v2 = *(const half8*)(P + nb + 64);
    half8 v3 = *(const half8*)(P + nb + 96);
#pragma unroll
    for (int i = 0; i < 8; ++i) {
      float f0 = (float)v0[i], f1 = (float)v1[i];
      float f2 = (float)v2[i], f3 = (float)v3[i];
      if (UA) {
        f0 = fmaxf(fmaf(af[0][i], f0, cf[0][i]), 0.f);
        f1 = fmaxf(fmaf(af[1][i], f1, cf[1][i]), 0.f);
        f2 = fmaxf(fmaf(af[2][i], f2, cf[2][i]), 0.f);
        f3 = fmaxf(fmaf(af[3][i], f3, cf[3][i]), 0.f);
      }
      acc[0][i] += f0; acc[1][i] += f1; acc[2][i] += f2; acc[3][i] += f3;
    }
  }
  half8 xf[4];
#pragma unroll
  for (int kt = 0; kt < 4; ++kt)
#pragma unroll
    for (int i = 0; i < 8; ++i) xf[kt][i] = (_Float16)acc[kt][i];
  __syncthreads();   // W1 staged (agg touched no LDS)

  // GEMM1: t = relu(x @ W1 + b1) -> tbuf (fp16, swizzled)
#pragma unroll
  for (int ct = 0; ct < 8; ++ct) {
    int n = ct * 16 + l15;
    float bv = b1[n];
    f32x4 acc1 = {bv, bv, bv, bv};
#pragma unroll
    for (int kt = 0; kt < 4; ++kt) {
      int hidx = (n * DIM + kt * 32 + 8 * h) ^ ((n & 7) << 3);
      half8 bf = *(const half8*)(wbuf + hidx);
      acc1 = __builtin_amdgcn_mfma_f32_16x16x32_f16(xf[kt], bf, acc1, 0, 0, 0);
    }
#pragma unroll
    for (int r = 0; r < 4; ++r) {
      int lr = 16 * w + 4 * h + r;
      int ti = (lr * DIM + n) ^ ((lr & 7) << 3);
      tb[ti] = (_Float16)fmaxf(acc1[r], 0.f);
    }
  }
  __syncthreads();           // tbuf complete; wbuf (W1) dead

  // stage W2^T into the same buffer + load t fragments
#pragma unroll
  for (int i = 0; i < 8; ++i) {
    int h8 = 2048 + i * 256 + tid;     // W2 half8s
    half8 v = wg[h8];
    int idx8 = h8 & 2047;
    int cc = idx8 >> 4, k8 = idx8 & 15;
    int hidx = (cc * DIM + k8 * 8) ^ ((cc & 7) << 3);
    *(half8*)(wbuf + hidx) = v;
  }
  half8 tf[4];
#pragma unroll
  for (int kt = 0; kt < 4; ++kt) {
    int lr = 16 * w + l15;
    int ti = (lr * DIM + kt * 32 + 8 * h) ^ ((lr & 7) << 3);
    tf[kt] = *(const half8*)(tb + ti);
  }
  __syncthreads();           // W2 staged; all tf loaded -> tb reusable for z

  // GEMM2: z = t @ W2 + b2 -> tb (fp16) + stats in regs
  float sa[8], qa[8];
#pragma unroll
  for (int ct = 0; ct < 8; ++ct) {
    int n = ct * 16 + l15;
    float bv = b2[n];
    f32x4 acc2 = {bv, bv, bv, bv};
#pragma unroll
    for (int kt = 0; kt < 4; ++kt) {
      int hidx = (n * DIM + kt * 32 + 8 * h) ^ ((n & 7) << 3);
      half8 bf = *(const half8*)(wbuf + hidx);
      acc2 = __builtin_amdgcn_mfma_f32_16x16x32_f16(tf[kt], bf, acc2, 0, 0, 0);
    }
    float s = 0.f, q = 0.f;
#pragma unroll
    for (int r = 0; r < 4; ++r) {
      int lr = 16 * w + 4 * h + r;
      float y = acc2[r];
      int ti = (lr * DIM + n) ^ ((lr & 7) << 3);
      tb[ti] = (_Float16)y;
      s += y; q += y * y;
    }
    sa[ct] = s; qa[ct] = q;
  }
  __syncthreads();           // GEMM2 done; wbuf dead -> reuse for stats

  float* sst = (float*)sh;
  sst[tid] = 0.f;
  __syncthreads();
  // reduce stats: shfl across h-groups -> LDS -> sliced global atomics
#pragma unroll
  for (int ct = 0; ct < 8; ++ct) {
    float s = sa[ct], q = qa[ct];
    s += __shfl_xor(s, 16); s += __shfl_xor(s, 32);
    q += __shfl_xor(q, 16); q += __shfl_xor(q, 32);
    if (h == 0) {
      int n = ct * 16 + l15;
      atomicAdd(&sst[n], s);
      atomicAdd(&sst[DIM + n], q);
    }
  }
  __syncthreads();           // z tile + sst complete

  // coalesced fp16 row stores from tb
#pragma unroll
  for (int i = 0; i < 4; ++i) {
    int chunk = i * 256 + tid;         // 0..1023
    int lr = chunk >> 4, k8 = chunk & 15;
    int ti = (lr * DIM + k8 * 8) ^ ((lr & 7) << 3);
    half8 v = *(const half8*)(tb + ti);
    *(half8*)(Z + (size_t)(blockIdx.x * 64 + lr) * DIM + k8 * 8) = v;
  }
  atomicAdd(&stats[(blockIdx.x & 63) * 256 + tid], sst[tid]);
}

// ---------------- finalize BN -> affine a,c ----------------
__global__ __launch_bounds__(128) void k_fin(const float* __restrict__ stats, const float* __restrict__ gamma,
                                             const float* __restrict__ beta, float* __restrict__ affine) {
  int c = threadIdx.x;   // 128
  float s = 0.f, q = 0.f;
  for (int i = 0; i < 64; ++i) {
    s += stats[i * 256 + c];
    q += stats[i * 256 + DIM + c];
  }
  float mean = s / (float)N_NODES;
  float var = q / (float)N_NODES - mean * mean;
  float inv = 1.f / sqrtf(var + BN_EPS);
  float a = gamma[c] * inv;
  affine[c] = a;
  affine[DIM + c] = beta[c] - mean * a;
}

// ---------------- final: out = a*z + c (no relu), fp32 out ----------------
__global__ __launch_bounds__(256) void k_out(const _Float16* __restrict__ z, const float* __restrict__ affine,
                                             float* __restrict__ out) {
  int idx = blockIdx.x * 256 + threadIdx.x;   // 4-col chunk
  int c4 = (idx & 31) * 4;
  half4 v = *(const half4*)(z + (size_t)idx * 4);
  float4 a = *(const float4*)(affine + c4);
  float4 c = *(const float4*)(affine + DIM + c4);
  float4 r;
  r.x = fmaf(a.x, (float)v[0], c.x); r.y = fmaf(a.y, (float)v[1], c.y);
  r.z = fmaf(a.z, (float)v[2], c.z); r.w = fmaf(a.w, (float)v[3], c.w);
  *(float4*)(out + (size_t)idx * 4) = r;
}

extern "C" void kernel_launch(void* const* d_in, const int* in_sizes, int n_in,
                              void* d_out, int out_size, void* d_ws, size_t ws_size,
                              hipStream_t stream) {
  const int*   x     = (const int*)d_in[0];
  const int*   ei    = (const int*)d_in[1];
  // d_in[2] = edge_attr: unused by the reference
  const float* ea    = (const float*)d_in[3];
  const float* ec    = (const float*)d_in[4];
  const float* W1    = (const float*)d_in[5];
  const float* b1    = (const float*)d_in[6];
  const float* W2    = (const float*)d_in[7];
  const float* b2    = (const float*)d_in[8];
  const float* gamma = (const float*)d_in[9];
  const float* beta  = (const float*)d_in[10];
  const int* src = ei;
  const int* dst = ei + N_EDGES;

  char* ws = (char*)d_ws;
  size_t off = 0;
  auto take = [&](size_t b) { char* p = ws + off; off += (b + 255) & ~(size_t)255; return p; };
  _Float16* Z0     = (_Float16*)take((size_t)N_NODES * DIM * 2);
  _Float16* Z1     = (_Float16*)take((size_t)N_NODES * DIM * 2);
  _Float16* wt     = (_Float16*)take((size_t)NLAYER * 2 * DIM * DIM * 2);
  int*      rp     = (int*)take((size_t)(N_NODES + 1) * 4);
  int*      fill   = (int*)take((size_t)N_NODES * 4);
  int*      es     = (int*)take((size_t)N_EDGES * 4);
  int*      part   = (int*)take(4096);
  float*    stats  = (float*)take(64 * 256 * 4);
  float*    affine = (float*)take(256 * 4);
  if (off > ws_size) return;

  const int NB1 = (N_NODES + 1023) / 1024;   // 391

  // CSR build (once per launch; reused across all 5 layers)
  hipMemsetAsync(fill, 0, (size_t)N_NODES * 4, stream);
  k_hist<<<(N_EDGES + 255) / 256, 256, 0, stream>>>(dst, fill);
  k_scan1<<<NB1, 256, 0, stream>>>(fill, rp, part);
  k_scan2<<<1, 512, 0, stream>>>(part, NB1);
  k_scan3<<<(N_NODES + 255) / 256, 256, 0, stream>>>(rp, part);
  hipMemsetAsync(fill, 0, (size_t)N_NODES * 4, stream);
  k_scatter<<<(N_EDGES + 255) / 256, 256, 0, stream>>>(src, dst, rp, fill, es);

  k_embed<<<N_NODES * 16 / 256, 256, 0, stream>>>(x, ea, ec, Z0);
  k_wprep<<<NLAYER * 2 * DIM, DIM, 0, stream>>>(W1, W2, wt);

  _Float16* pin = Z0;
  _Float16* pout = Z1;
  for (int l = 0; l < NLAYER; ++l) {
    hipMemsetAsync(stats, 0, 64 * 256 * 4, stream);
    if (l == 0)
      k_layer<0><<<N_NODES / 64, 256, 0, stream>>>(pin, rp, es, affine,
                                                   wt + (size_t)l * 2 * DIM * DIM,
                                                   b1 + l * DIM, b2 + l * DIM, pout, stats);
    else
      k_layer<1><<<N_NODES / 64, 256, 0, stream>>>(pin, rp, es, affine,
                                                   wt + (size_t)l * 2 * DIM * DIM,
                                                   b1 + l * DIM, b2 + l * DIM, pout, stats);
    k_fin<<<1, DIM, 0, stream>>>(stats, gamma + l * DIM, beta + l * DIM, affine);
    _Float16* t = pin; pin = pout; pout = t;
  }
  k_out<<<N_NODES * 32 / 256, 256, 0, stream>>>(pin, affine, (float*)d_out);
}